// Round 15
// baseline (266.488 us; speedup 1.0000x reference)
//
#include <hip/hip_runtime.h>
#include <hip/hip_bf16.h>

#define NB   8
#define NPTS 16384
#define NS1  512
#define NS2  128
#define KNN  32
#define FINF 3.402823466e+38f
#define NINF_BITS ((int)0xFF800000)

// Distributed exact running top-32 across lanes 0..31: f32 key + carried idx.
// STABLE insert + strict < vs tau == lexicographic (d, idx) when candidates
// arrive in ascending idx order. Scan variant: candidate idx = jbase + src.
__device__ __forceinline__ void topk32f_scan(float key, int jbase, int lane,
                                             float& lkey, int& lidx, float& tau,
                                             unsigned long long mask) {
  const bool is16 = (lane == 16);
  while (mask) {
    const int src = (int)(__ffsll((long long)mask) - 1);   // wave-uniform
    mask &= mask - 1;
    const float ck = __int_as_float(
        __builtin_amdgcn_readlane(__float_as_int(key), src));
    if (ck < tau) {
      const int ci = jbase + src;                          // SALU, no readlane
      const int upk0 = __builtin_amdgcn_update_dpp(
          NINF_BITS, __float_as_int(lkey), 0x111, 0xf, 0xf, false);
      const int upi0 = __builtin_amdgcn_update_dpp(
          0, lidx, 0x111, 0xf, 0xf, false);
      const int pk = __builtin_amdgcn_readlane(__float_as_int(lkey), 15);
      const int pi = __builtin_amdgcn_readlane(lidx, 15);
      const float up  = __int_as_float(is16 ? pk : upk0);
      const int   upi = is16 ? pi : upi0;
      const bool keep  = (lkey <= ck);
      const bool useup = (up > ck);
      const float nk = keep ? lkey : (useup ? up : ck);
      const int   ni = keep ? lidx : (useup ? upi : ci);
      if (lane < 32) { lkey = nk; lidx = ni; }
      tau = __int_as_float(__builtin_amdgcn_readlane(__float_as_int(lkey), 31));
    }
  }
}

// Merge variant: candidate idx is arbitrary (gathered) -> readlane it.
__device__ __forceinline__ void topk32f_merge(float key, int idx, int lane,
                                              float& lkey, int& lidx, float& tau,
                                              unsigned long long mask) {
  const bool is16 = (lane == 16);
  while (mask) {
    const int src = (int)(__ffsll((long long)mask) - 1);
    mask &= mask - 1;
    const float ck = __int_as_float(
        __builtin_amdgcn_readlane(__float_as_int(key), src));
    if (ck < tau) {
      const int ci = __builtin_amdgcn_readlane(idx, src);
      const int upk0 = __builtin_amdgcn_update_dpp(
          NINF_BITS, __float_as_int(lkey), 0x111, 0xf, 0xf, false);
      const int upi0 = __builtin_amdgcn_update_dpp(
          0, lidx, 0x111, 0xf, 0xf, false);
      const int pk = __builtin_amdgcn_readlane(__float_as_int(lkey), 15);
      const int pi = __builtin_amdgcn_readlane(lidx, 15);
      const float up  = __int_as_float(is16 ? pk : upk0);
      const int   upi = is16 ? pi : upi0;
      const bool keep  = (lkey <= ck);
      const bool useup = (up > ck);
      const float nk = keep ? lkey : (useup ? up : ck);
      const int   ni = keep ? lidx : (useup ? upi : ci);
      if (lane < 32) { lkey = nk; lidx = ni; }
      tau = __int_as_float(__builtin_amdgcn_readlane(__float_as_int(lkey), 31));
    }
  }
}

// Merge this lane's sorted top-3 (d,j) with xor-partner's, lexicographic (d, j).
__device__ __forceinline__ void merge3(float& d0, int& j0, float& d1, int& j1,
                                       float& d2, int& j2, int xm) {
  float e0 = __shfl_xor(d0, xm), e1 = __shfl_xor(d1, xm), e2 = __shfl_xor(d2, xm);
  int   f0 = __shfl_xor(j0, xm), f1 = __shfl_xor(j1, xm), f2 = __shfl_xor(j2, xm);
  float a0 = d0, a1 = d1, a2 = d2;
  int   b0 = j0, b1 = j1, b2 = j2;
  float od0, od1, od2; int oj0, oj1, oj2;
  #pragma unroll
  for (int r = 0; r < 3; ++r) {
    bool ta = (a0 < e0) || (a0 == e0 && b0 < f0);
    float sd = ta ? a0 : e0; int sj = ta ? b0 : f0;
    a0 = ta ? a1 : a0;  b0 = ta ? b1 : b0;
    a1 = ta ? a2 : a1;  b1 = ta ? b2 : b1;
    a2 = ta ? FINF : a2;
    e0 = ta ? e0 : e1;  f0 = ta ? f0 : f1;
    e1 = ta ? e1 : e2;  f1 = ta ? f1 : f2;
    e2 = ta ? e2 : FINF;
    if (r == 0) { od0 = sd; oj0 = sj; }
    else if (r == 1) { od1 = sd; oj1 = sj; }
    else { od2 = sd; oj2 = sj; }
  }
  d0 = od0; j0 = oj0; d1 = od1; j1 = oj1; d2 = od2; j2 = oj2;
}

// ---------------- prep: xr[i] = (x, y, z, x^2+y^2+z^2) for all B*N points ----
extern "C" __global__ void __launch_bounds__(256)
prep_kernel(const float* __restrict__ x, float4* __restrict__ xr) {
  const int i = blockIdx.x * 256 + threadIdx.x;   // 0..131071
  const float rx = x[i*3+0], ry = x[i*3+1], rz = x[i*3+2];
  xr[i] = make_float4(rx, ry, rz, rx*rx + ry*ry + rz*rz);
}

// per-tile distance + top-32 maintenance (f32 key, idx = jbase + src)
#define PROCF(rr, jbase)                                                      \
  {                                                                           \
    const float d = (Q.w - 2.0f*(Q.x*rr.x + Q.y*rr.y + Q.z*rr.z)) + rr.w;     \
    const unsigned long long mask = __ballot(d < tau);                        \
    if (mask) topk32f_scan(d, (jbase), lane, lkey, lidx, tau, mask);          \
  }

// ---- kNN 1: wave-per-query, 8-deep prefetch ring, per-insert tau,
// ---- 32-bit f32 stable insert (DPP + readlane; no LDS). [R11-proven: 88us]
extern "C" __global__ void __launch_bounds__(256)
knn1_kernel(const float4* __restrict__ xr, const int* __restrict__ sidx1,
            int* __restrict__ idx1) {
  const int w = threadIdx.x >> 6, lane = threadIdx.x & 63;
  const int gq = blockIdx.x * 4 + w;          // 0..4095
  const int b = gq >> 9, q = gq & (NS1 - 1);
  const float4* xb = xr + (size_t)b * NPTS;
  const float4 Q = xb[sidx1[q]];
  float lkey = FINF, tau = FINF;
  int lidx = 0;
  float4 r0 = xb[0*64+lane], r1 = xb[1*64+lane], r2 = xb[2*64+lane], r3 = xb[3*64+lane];
  float4 r4 = xb[4*64+lane], r5 = xb[5*64+lane], r6 = xb[6*64+lane], r7 = xb[7*64+lane];
  for (int t = 0; t < 256; t += 8) {
    PROCF(r0, (t+0)*64);  r0 = xb[((t+ 8)&255)*64 + lane];
    PROCF(r1, (t+1)*64);  r1 = xb[((t+ 9)&255)*64 + lane];
    PROCF(r2, (t+2)*64);  r2 = xb[((t+10)&255)*64 + lane];
    PROCF(r3, (t+3)*64);  r3 = xb[((t+11)&255)*64 + lane];
    PROCF(r4, (t+4)*64);  r4 = xb[((t+12)&255)*64 + lane];
    PROCF(r5, (t+5)*64);  r5 = xb[((t+13)&255)*64 + lane];
    PROCF(r6, (t+6)*64);  r6 = xb[((t+14)&255)*64 + lane];
    PROCF(r7, (t+7)*64);  r7 = xb[((t+15)&255)*64 + lane];
  }
  if (lane < 32) idx1[gq*KNN + lane] = lidx;
}

// ---------------- MLP1 (3->64 relu ->64) + maxpool over 32 nbrs ---------------
extern "C" __global__ void __launch_bounds__(256)
mlp1_kernel(const float* __restrict__ x, const int* __restrict__ sidx1,
            const int* __restrict__ idx1,
            const float* __restrict__ W1, const float* __restrict__ b1,
            const float* __restrict__ W2, const float* __restrict__ b2,
            float* __restrict__ feat1, float* __restrict__ rr1,
            float* __restrict__ samp1) {
  __shared__ float P[32][3];
  __shared__ float H[32][64];
  __shared__ float PM[4][64];
  const int tid = threadIdx.x;
  const int gq = blockIdx.x;                  // 0..4095
  const int b = gq >> 9, q = gq & (NS1-1);
  const float* xb = x + (size_t)b * NPTS * 3;
  const int* nb = idx1 + gq * KNN;
  if (tid < 96) { int n = tid/3, d = tid - n*3; P[n][d] = xb[nb[n]*3 + d]; }
  __syncthreads();
  #pragma unroll
  for (int i = 0; i < 8; ++i) {
    int e = tid + 256*i, n = e >> 6, c = e & 63;
    float h = b1[c] + P[n][0]*W1[c] + P[n][1]*W1[64+c] + P[n][2]*W1[128+c];
    H[n][c] = fmaxf(h, 0.0f);
  }
  __syncthreads();
  const int g = tid >> 6, c = tid & 63;
  float acc[8];
  #pragma unroll
  for (int k = 0; k < 8; ++k) acc[k] = 0.0f;
  for (int j = 0; j < 64; j += 4) {
    float w0 = W2[j*64+c], w1 = W2[(j+1)*64+c], w2 = W2[(j+2)*64+c], w3 = W2[(j+3)*64+c];
    #pragma unroll
    for (int k = 0; k < 8; ++k) {
      float4 h4 = *(const float4*)&H[g*8+k][j];
      acc[k] = fmaf(h4.w, w3, fmaf(h4.z, w2, fmaf(h4.y, w1, fmaf(h4.x, w0, acc[k]))));
    }
  }
  float m = acc[0];
  #pragma unroll
  for (int k = 1; k < 8; ++k) m = fmaxf(m, acc[k]);
  PM[g][c] = m;
  __syncthreads();
  if (tid < 64) {
    float v = fmaxf(fmaxf(PM[0][tid], PM[1][tid]), fmaxf(PM[2][tid], PM[3][tid])) + b2[tid];
    feat1[(size_t)gq*64 + tid] = v;
    float s = v*v;
    #pragma unroll
    for (int off = 32; off; off >>= 1) s += __shfl_xor(s, off);
    if (tid == 0) rr1[gq] = s;
  } else if (tid < 67) {
    int d = tid - 64;
    samp1[(size_t)gq*3 + d] = xb[sidx1[q]*3 + d];
  }
}

// ---- FUSED kNN2 + MLP2: block per query (1024 blocks).
extern "C" __global__ void __launch_bounds__(256)
knn2mlp2_kernel(const float* __restrict__ feat1, const float* __restrict__ rr1,
                const int* __restrict__ sidx2,
                const float* __restrict__ W1, const float* __restrict__ b1,
                const float* __restrict__ W2, const float* __restrict__ b2,
                float* __restrict__ feat2) {
  __shared__ float qrow[64];
  __shared__ float SK[4][32];
  __shared__ int   SI[4][32];
  __shared__ int   NBs[32];
  __shared__ float Gm[32][64];
  __shared__ float H[32][128];
  __shared__ float PM[2][128];
  const int tid = threadIdx.x, w = tid >> 6, lane = tid & 63;
  const int gq = blockIdx.x;                  // 0..1023
  const int b = gq >> 7, q = gq & (NS2-1);
  const float* f1b = feat1 + (size_t)b * NS1 * 64;
  const float* rrb = rr1 + b * NS1;
  const int sq = sidx2[q];
  if (tid < 64) qrow[tid] = f1b[sq*64 + tid];
  __syncthreads();
  const float qq = rrb[sq];
  float lkey = FINF, tau = FINF;
  int lidx = 0;
  #pragma unroll
  for (int t = 0; t < 2; ++t) {
    const int jb = w*128 + t*64;
    const int j = jb + lane;
    const float* rrow = f1b + j*64;
    float dot = 0.0f;
    #pragma unroll
    for (int f = 0; f < 64; f += 4) {
      float4 r4 = *(const float4*)(rrow + f);
      dot = fmaf(qrow[f+3], r4.w, fmaf(qrow[f+2], r4.z,
            fmaf(qrow[f+1], r4.y, fmaf(qrow[f+0], r4.x, dot))));
    }
    const float d = (qq - 2.0f*dot) + rrb[j];
    const unsigned long long mask = __ballot(d < tau);
    if (mask) topk32f_scan(d, jb, lane, lkey, lidx, tau, mask);
  }
  if (lane < 32) { SK[w][lane] = lkey; SI[w][lane] = lidx; }
  __syncthreads();
  if (w == 0) {
    #pragma unroll
    for (int ww = 1; ww < 4; ++ww) {
      const float mk = (lane < 32) ? SK[ww][lane] : FINF;
      const int   mi = (lane < 32) ? SI[ww][lane] : 0;
      const unsigned long long mmask = __ballot(mk < tau);
      if (mmask) topk32f_merge(mk, mi, lane, lkey, lidx, tau, mmask);
    }
    if (lane < 32) NBs[lane] = lidx;
  }
  __syncthreads();
  #pragma unroll
  for (int i = 0; i < 8; ++i) {
    int e = tid + 256*i, n = e >> 6, f = e & 63;
    Gm[n][f] = f1b[NBs[n]*64 + f];
  }
  __syncthreads();
  #pragma unroll
  for (int i = 0; i < 16; ++i) {
    int e = tid + 256*i, n = e >> 7, c = e & 127;
    float h = b1[c];
    for (int f = 0; f < 64; f += 4) {
      float4 g4 = *(const float4*)&Gm[n][f];
      h = fmaf(g4.x, W1[f*128+c], h);
      h = fmaf(g4.y, W1[(f+1)*128+c], h);
      h = fmaf(g4.z, W1[(f+2)*128+c], h);
      h = fmaf(g4.w, W1[(f+3)*128+c], h);
    }
    H[n][c] = fmaxf(h, 0.0f);
  }
  __syncthreads();
  const int g = tid >> 7, c = tid & 127;
  float acc[16];
  #pragma unroll
  for (int k = 0; k < 16; ++k) acc[k] = 0.0f;
  for (int j = 0; j < 128; j += 4) {
    float w0 = W2[j*128+c], w1 = W2[(j+1)*128+c], w2 = W2[(j+2)*128+c], w3 = W2[(j+3)*128+c];
    #pragma unroll
    for (int k = 0; k < 16; ++k) {
      float4 h4 = *(const float4*)&H[g*16+k][j];
      acc[k] = fmaf(h4.w, w3, fmaf(h4.z, w2, fmaf(h4.y, w1, fmaf(h4.x, w0, acc[k]))));
    }
  }
  float m = acc[0];
  #pragma unroll
  for (int k = 1; k < 16; ++k) m = fmaxf(m, acc[k]);
  PM[g][c] = m;
  __syncthreads();
  if (tid < 128) feat2[(size_t)gq*128 + tid] = fmaxf(PM[0][tid], PM[1][tid]) + b2[tid];
}

// ------- fp1: kNN(samp1 vs coords2, k=3) + mean(feat2) + MLP(192->64 relu ->64)
extern "C" __global__ void __launch_bounds__(256)
fp1_kernel(const float* __restrict__ samp1, const int* __restrict__ sidx2,
           const float* __restrict__ feat1, const float* __restrict__ feat2,
           const float* __restrict__ W1, const float* __restrict__ b1,
           const float* __restrict__ W2, const float* __restrict__ b2,
           float* __restrict__ h1) {
  __shared__ float interp[4][128];
  __shared__ float hbuf[4][64];
  const int w = threadIdx.x >> 6, lane = threadIdx.x & 63;
  const int gq = blockIdx.x*4 + w;            // 0..4095
  const int b = gq >> 9, q = gq & (NS1-1);
  const float* s1b = samp1 + (size_t)b * NS1 * 3;
  const float qx = s1b[q*3+0], qy = s1b[q*3+1], qz = s1b[q*3+2];
  const float qq = qx*qx + qy*qy + qz*qz;
  float d0, d1; int j0i, j1i;
  {
    const int rs = sidx2[lane];
    const float rx = s1b[rs*3+0], ry = s1b[rs*3+1], rz = s1b[rs*3+2];
    d0 = (qq - 2.0f*(qx*rx+qy*ry+qz*rz)) + (rx*rx+ry*ry+rz*rz);
    j0i = lane;
  }
  {
    const int j = lane + 64;
    const int rs = sidx2[j];
    const float rx = s1b[rs*3+0], ry = s1b[rs*3+1], rz = s1b[rs*3+2];
    d1 = (qq - 2.0f*(qx*rx+qy*ry+qz*rz)) + (rx*rx+ry*ry+rz*rz);
    j1i = j;
  }
  if (d1 < d0) { float td = d0; d0 = d1; d1 = td; int tj = j0i; j0i = j1i; j1i = tj; }
  float dA = d0, dB = d1, dC = FINF;
  int   jA = j0i, jB = j1i, jC = 0;
  merge3(dA, jA, dB, jB, dC, jC, 1);
  merge3(dA, jA, dB, jB, dC, jC, 2);
  merge3(dA, jA, dB, jB, dC, jC, 4);
  merge3(dA, jA, dB, jB, dC, jC, 8);
  merge3(dA, jA, dB, jB, dC, jC, 16);
  merge3(dA, jA, dB, jB, dC, jC, 32);
  const int r0 = jA, r1 = jB, r2 = jC;
  const float* f2b = feat2 + (size_t)b * NS2 * 128;
  interp[w][lane] =
      (f2b[r0*128+lane] + f2b[r1*128+lane] + f2b[r2*128+lane]) * (1.0f/3.0f);
  interp[w][lane+64] =
      (f2b[r0*128+64+lane] + f2b[r1*128+64+lane] + f2b[r2*128+64+lane]) * (1.0f/3.0f);
  __syncthreads();
  const float* f1row = feat1 + (size_t)gq * 64;
  float h = b1[lane];
  for (int f = 0; f < 64; ++f)  h = fmaf(f1row[f], W1[f*64+lane], h);
  for (int f = 0; f < 128; ++f) h = fmaf(interp[w][f], W1[(64+f)*64+lane], h);
  hbuf[w][lane] = fmaxf(h, 0.0f);
  __syncthreads();
  float o = b2[lane];
  for (int f = 0; f < 64; ++f) o = fmaf(hbuf[w][f], W2[f*64+lane], o);
  h1[(size_t)gq*64 + lane] = o;
}

// ---- FUSED fp2: 32 points/block, 8 threads/point kNN (64 refs each) + interp
// ---- + MLP(67->32 relu) @ folded (W2@fc) + sigmoid. LDS ~30KB -> 5 blocks/CU.
extern "C" __global__ void __launch_bounds__(256, 5)
fp2_kernel(const float* __restrict__ x, const float* __restrict__ samp1,
           const float* __restrict__ h1,
           const float* __restrict__ W1, const float* __restrict__ b1,
           const float* __restrict__ W2, const float* __restrict__ b2,
           const float* __restrict__ fcW, const float* __restrict__ fcb,
           float* __restrict__ out) {
  __shared__ float4 RS[NS1];       // 8 KB
  __shared__ ushort4 kid[32];
  __shared__ float Xe[32][68];     // 8.7 KB
  __shared__ float W1s[67*32];     // 8.6 KB
  __shared__ float Hs[32][36];     // 4.6 KB
  __shared__ float WcS[64];
  __shared__ float bcS[2];
  const int tid = threadIdx.x;
  const int b = blockIdx.x >> 9;              // 512 blocks per batch
  const int pbase = (blockIdx.x & 511) * 32;
  const float* xb = x + (size_t)b * NPTS * 3;
  const float* h1b = h1 + (size_t)b * NS1 * 64;
  for (int e = tid; e < NS1; e += 256) {
    const float rx = samp1[((size_t)b*NS1 + e)*3 + 0];
    const float ry = samp1[((size_t)b*NS1 + e)*3 + 1];
    const float rz = samp1[((size_t)b*NS1 + e)*3 + 2];
    RS[e] = make_float4(rx, ry, rz, rx*rx + ry*ry + rz*rz);
  }
  for (int e = tid; e < 67*32; e += 256) W1s[e] = W1[e];
  if (tid < 96) {
    int n = tid/3, d = tid - n*3;
    Xe[n][d] = xb[(pbase+n)*3 + d];
  }
  __syncthreads();
  // ---- phase 1: top-3, 8 threads/point x 64 refs, 3-level shfl merge ----
  {
    const int pl = tid >> 3, q8 = tid & 7;
    const float qx = Xe[pl][0], qy = Xe[pl][1], qz = Xe[pl][2];
    const float qq = qx*qx + qy*qy + qz*qz;
    float d0 = FINF, d1 = FINF, d2 = FINF;
    int j0 = 0, j1 = 0, j2 = 0;
    const float4* RQ = RS + q8*64;
    #pragma unroll 4
    for (int i = 0; i < 64; ++i) {
      const float4 r = RQ[i];
      const float dot = qx*r.x + qy*r.y + qz*r.z;
      const float d = (qq - 2.0f*dot) + r.w;
      const int j = q8*64 + i;
      const bool c2 = d < d2, c1 = d < d1, c0 = d < d0;
      d2 = c1 ? d1 : (c2 ? d : d2);  j2 = c1 ? j1 : (c2 ? j : j2);
      d1 = c0 ? d0 : (c1 ? d : d1);  j1 = c0 ? j0 : (c1 ? j : j1);
      d0 = c0 ? d : d0;              j0 = c0 ? j : j0;
    }
    merge3(d0, j0, d1, j1, d2, j2, 1);
    merge3(d0, j0, d1, j1, d2, j2, 2);
    merge3(d0, j0, d1, j1, d2, j2, 4);
    if (q8 == 0) {
      ushort4 o;
      o.x = (unsigned short)j0; o.y = (unsigned short)j1;
      o.z = (unsigned short)j2; o.w = 0;
      kid[pl] = o;
    }
  }
  __syncthreads();
  // ---- phase 2: interp (32 pts x 64 feats) ----
  {
    const int sub = tid >> 6, f = tid & 63;
    #pragma unroll 4
    for (int i = 0; i < 8; ++i) {
      const int p = i*4 + sub;
      const ushort4 kk = kid[p];
      const float v = (h1b[(int)kk.x*64 + f] + h1b[(int)kk.y*64 + f] +
                       h1b[(int)kk.z*64 + f]) * (1.0f/3.0f);
      Xe[p][3+f] = v;
    }
  }
  __syncthreads();
  if (tid < 64) {
    const int k = tid >> 1, col = tid & 1;
    float s = 0.0f;
    for (int c = 0; c < 32; ++c) s = fmaf(W2[k*32+c], fcW[c*2+col], s);
    WcS[k*2+col] = s;
  } else if (tid < 66) {
    const int col = tid & 1;
    float s = fcb[col];
    for (int c = 0; c < 32; ++c) s = fmaf(b2[c], fcW[c*2+col], s);
    bcS[col] = s;
  }
  // ---- phase 3: hidden layer, 8 threads/point x 4 channels ----
  {
    const int p = tid >> 3, c0 = (tid & 7) * 4;
    float acc[4];
    const float4 bb = *(const float4*)(b1 + c0);
    acc[0]=bb.x; acc[1]=bb.y; acc[2]=bb.z; acc[3]=bb.w;
    for (int f = 0; f < 67; ++f) {
      const float xv = Xe[p][f];
      const float4 w0 = *(const float4*)&W1s[f*32 + c0];
      acc[0] = fmaf(xv, w0.x, acc[0]);
      acc[1] = fmaf(xv, w0.y, acc[1]);
      acc[2] = fmaf(xv, w0.z, acc[2]);
      acc[3] = fmaf(xv, w0.w, acc[3]);
    }
    *(float4*)&Hs[p][c0] = make_float4(fmaxf(acc[0],0.f), fmaxf(acc[1],0.f),
                                       fmaxf(acc[2],0.f), fmaxf(acc[3],0.f));
  }
  __syncthreads();
  // ---- phase 4: folded fc + sigmoid (32 pts x 2 cols) ----
  if (tid < 64) {
    const int p = tid >> 1, col = tid & 1;
    float s = bcS[col];
    for (int c = 0; c < 32; ++c) s = fmaf(Hs[p][c], WcS[c*2+col], s);
    out[((size_t)b*NPTS + pbase + p)*2 + col] = 1.0f / (1.0f + expf(-s));
  }
}

extern "C" void kernel_launch(void* const* d_in, const int* in_sizes, int n_in,
                              void* d_out, int out_size, void* d_ws, size_t ws_size,
                              hipStream_t stream) {
  const float* x     = (const float*)d_in[0];
  const int*   sidx1 = (const int*)d_in[1];
  const int*   sidx2 = (const int*)d_in[2];
  const float* sa1W1 = (const float*)d_in[3];
  const float* sa1b1 = (const float*)d_in[4];
  const float* sa1W2 = (const float*)d_in[5];
  const float* sa1b2 = (const float*)d_in[6];
  const float* sa2W1 = (const float*)d_in[7];
  const float* sa2b1 = (const float*)d_in[8];
  const float* sa2W2 = (const float*)d_in[9];
  const float* sa2b2 = (const float*)d_in[10];
  const float* fp1W1 = (const float*)d_in[11];
  const float* fp1b1 = (const float*)d_in[12];
  const float* fp1W2 = (const float*)d_in[13];
  const float* fp1b2 = (const float*)d_in[14];
  const float* fp2W1 = (const float*)d_in[15];
  const float* fp2b1 = (const float*)d_in[16];
  const float* fp2W2 = (const float*)d_in[17];
  const float* fp2b2 = (const float*)d_in[18];
  const float* fcW   = (const float*)d_in[19];
  const float* fcb   = (const float*)d_in[20];
  float* out = (float*)d_out;

  char* ws = (char*)d_ws;
  float4* xr   = (float4*)(ws + 0);         // 8*16384*16 = 2,097,152 B
  float* feat1 = (float*)(ws + 0);          // overlap: xr dead after knn1
  float* rr1   = (float*)(ws + 1048576);
  float* samp1 = (float*)(ws + 1064960);
  float* feat2 = (float*)(ws + 1114112);
  float* h1    = (float*)(ws + 1638400);
  int*   idx1  = (int*)  (ws + 2686976);

  hipLaunchKernelGGL(prep_kernel, dim3(512), dim3(256), 0, stream, x, xr);
  hipLaunchKernelGGL(knn1_kernel, dim3(1024), dim3(256), 0, stream,
                     xr, sidx1, idx1);
  hipLaunchKernelGGL(mlp1_kernel, dim3(4096), dim3(256), 0, stream,
                     x, sidx1, idx1, sa1W1, sa1b1, sa1W2, sa1b2,
                     feat1, rr1, samp1);
  hipLaunchKernelGGL(knn2mlp2_kernel, dim3(1024), dim3(256), 0, stream,
                     feat1, rr1, sidx2, sa2W1, sa2b1, sa2W2, sa2b2, feat2);
  hipLaunchKernelGGL(fp1_kernel, dim3(1024), dim3(256), 0, stream,
                     samp1, sidx2, feat1, feat2, fp1W1, fp1b1, fp1W2, fp1b2, h1);
  hipLaunchKernelGGL(fp2_kernel, dim3(4096), dim3(256), 0, stream,
                     x, samp1, h1, fp2W1, fp2b1, fp2W2, fp2b2, fcW, fcb, out);
}

// Round 16
// 235.913 us; speedup vs baseline: 1.1296x; 1.1296x over previous
//
#include <hip/hip_runtime.h>
#include <hip/hip_bf16.h>

#define NB   8
#define NPTS 16384
#define NS1  512
#define NS2  128
#define KNN  32
#define FINF 3.402823466e+38f
#define NINF_BITS ((int)0xFF800000)

// Distributed exact running top-32 across lanes 0..31: f32 key + carried idx.
// STABLE insert + strict < vs tau == lexicographic (d, idx) when candidates
// arrive in ascending idx order. Scan variant: candidate idx = jbase + src.
__device__ __forceinline__ void topk32f_scan(float key, int jbase, int lane,
                                             float& lkey, int& lidx, float& tau,
                                             unsigned long long mask) {
  const bool is16 = (lane == 16);
  while (mask) {
    const int src = (int)(__ffsll((long long)mask) - 1);   // wave-uniform
    mask &= mask - 1;
    const float ck = __int_as_float(
        __builtin_amdgcn_readlane(__float_as_int(key), src));
    if (ck < tau) {
      const int ci = jbase + src;                          // SALU, no readlane
      const int upk0 = __builtin_amdgcn_update_dpp(
          NINF_BITS, __float_as_int(lkey), 0x111, 0xf, 0xf, false);
      const int upi0 = __builtin_amdgcn_update_dpp(
          0, lidx, 0x111, 0xf, 0xf, false);
      const int pk = __builtin_amdgcn_readlane(__float_as_int(lkey), 15);
      const int pi = __builtin_amdgcn_readlane(lidx, 15);
      const float up  = __int_as_float(is16 ? pk : upk0);
      const int   upi = is16 ? pi : upi0;
      const bool keep  = (lkey <= ck);
      const bool useup = (up > ck);
      const float nk = keep ? lkey : (useup ? up : ck);
      const int   ni = keep ? lidx : (useup ? upi : ci);
      if (lane < 32) { lkey = nk; lidx = ni; }
      tau = __int_as_float(__builtin_amdgcn_readlane(__float_as_int(lkey), 31));
    }
  }
}

// Merge variant: candidate idx is arbitrary (gathered) -> readlane it.
__device__ __forceinline__ void topk32f_merge(float key, int idx, int lane,
                                              float& lkey, int& lidx, float& tau,
                                              unsigned long long mask) {
  const bool is16 = (lane == 16);
  while (mask) {
    const int src = (int)(__ffsll((long long)mask) - 1);
    mask &= mask - 1;
    const float ck = __int_as_float(
        __builtin_amdgcn_readlane(__float_as_int(key), src));
    if (ck < tau) {
      const int ci = __builtin_amdgcn_readlane(idx, src);
      const int upk0 = __builtin_amdgcn_update_dpp(
          NINF_BITS, __float_as_int(lkey), 0x111, 0xf, 0xf, false);
      const int upi0 = __builtin_amdgcn_update_dpp(
          0, lidx, 0x111, 0xf, 0xf, false);
      const int pk = __builtin_amdgcn_readlane(__float_as_int(lkey), 15);
      const int pi = __builtin_amdgcn_readlane(lidx, 15);
      const float up  = __int_as_float(is16 ? pk : upk0);
      const int   upi = is16 ? pi : upi0;
      const bool keep  = (lkey <= ck);
      const bool useup = (up > ck);
      const float nk = keep ? lkey : (useup ? up : ck);
      const int   ni = keep ? lidx : (useup ? upi : ci);
      if (lane < 32) { lkey = nk; lidx = ni; }
      tau = __int_as_float(__builtin_amdgcn_readlane(__float_as_int(lkey), 31));
    }
  }
}

// Merge this lane's sorted top-3 (d,j) with xor-partner's, lexicographic (d, j).
__device__ __forceinline__ void merge3(float& d0, int& j0, float& d1, int& j1,
                                       float& d2, int& j2, int xm) {
  float e0 = __shfl_xor(d0, xm), e1 = __shfl_xor(d1, xm), e2 = __shfl_xor(d2, xm);
  int   f0 = __shfl_xor(j0, xm), f1 = __shfl_xor(j1, xm), f2 = __shfl_xor(j2, xm);
  float a0 = d0, a1 = d1, a2 = d2;
  int   b0 = j0, b1 = j1, b2 = j2;
  float od0, od1, od2; int oj0, oj1, oj2;
  #pragma unroll
  for (int r = 0; r < 3; ++r) {
    bool ta = (a0 < e0) || (a0 == e0 && b0 < f0);
    float sd = ta ? a0 : e0; int sj = ta ? b0 : f0;
    a0 = ta ? a1 : a0;  b0 = ta ? b1 : b0;
    a1 = ta ? a2 : a1;  b1 = ta ? b2 : b1;
    a2 = ta ? FINF : a2;
    e0 = ta ? e0 : e1;  f0 = ta ? f0 : f1;
    e1 = ta ? e1 : e2;  f1 = ta ? f1 : f2;
    e2 = ta ? e2 : FINF;
    if (r == 0) { od0 = sd; oj0 = sj; }
    else if (r == 1) { od1 = sd; oj1 = sj; }
    else { od2 = sd; oj2 = sj; }
  }
  d0 = od0; j0 = oj0; d1 = od1; j1 = oj1; d2 = od2; j2 = oj2;
}

// ---------------- prep: xr[i] = (x, y, z, x^2+y^2+z^2) for all B*N points ----
extern "C" __global__ void __launch_bounds__(256)
prep_kernel(const float* __restrict__ x, float4* __restrict__ xr) {
  const int i = blockIdx.x * 256 + threadIdx.x;   // 0..131071
  const float rx = x[i*3+0], ry = x[i*3+1], rz = x[i*3+2];
  xr[i] = make_float4(rx, ry, rz, rx*rx + ry*ry + rz*rz);
}

// per-tile distance + top-32 maintenance (f32 key, idx = jbase + src)
#define PROCF(rr, jbase)                                                      \
  {                                                                           \
    const float d = (Q.w - 2.0f*(Q.x*rr.x + Q.y*rr.y + Q.z*rr.z)) + rr.w;     \
    const unsigned long long mask = __ballot(d < tau);                        \
    if (mask) topk32f_scan(d, (jbase), lane, lkey, lidx, tau, mask);          \
  }

// ---- kNN 1: wave-per-query, 8-deep prefetch ring, per-insert tau,
// ---- 32-bit f32 stable insert (DPP + readlane; no LDS). [R11-proven: 88us]
extern "C" __global__ void __launch_bounds__(256)
knn1_kernel(const float4* __restrict__ xr, const int* __restrict__ sidx1,
            int* __restrict__ idx1) {
  const int w = threadIdx.x >> 6, lane = threadIdx.x & 63;
  const int gq = blockIdx.x * 4 + w;          // 0..4095
  const int b = gq >> 9, q = gq & (NS1 - 1);
  const float4* xb = xr + (size_t)b * NPTS;
  const float4 Q = xb[sidx1[q]];
  float lkey = FINF, tau = FINF;
  int lidx = 0;
  float4 r0 = xb[0*64+lane], r1 = xb[1*64+lane], r2 = xb[2*64+lane], r3 = xb[3*64+lane];
  float4 r4 = xb[4*64+lane], r5 = xb[5*64+lane], r6 = xb[6*64+lane], r7 = xb[7*64+lane];
  for (int t = 0; t < 256; t += 8) {
    PROCF(r0, (t+0)*64);  r0 = xb[((t+ 8)&255)*64 + lane];
    PROCF(r1, (t+1)*64);  r1 = xb[((t+ 9)&255)*64 + lane];
    PROCF(r2, (t+2)*64);  r2 = xb[((t+10)&255)*64 + lane];
    PROCF(r3, (t+3)*64);  r3 = xb[((t+11)&255)*64 + lane];
    PROCF(r4, (t+4)*64);  r4 = xb[((t+12)&255)*64 + lane];
    PROCF(r5, (t+5)*64);  r5 = xb[((t+13)&255)*64 + lane];
    PROCF(r6, (t+6)*64);  r6 = xb[((t+14)&255)*64 + lane];
    PROCF(r7, (t+7)*64);  r7 = xb[((t+15)&255)*64 + lane];
  }
  if (lane < 32) idx1[gq*KNN + lane] = lidx;
}

// ---------------- MLP1 (3->64 relu ->64) + maxpool over 32 nbrs ---------------
extern "C" __global__ void __launch_bounds__(256)
mlp1_kernel(const float* __restrict__ x, const int* __restrict__ sidx1,
            const int* __restrict__ idx1,
            const float* __restrict__ W1, const float* __restrict__ b1,
            const float* __restrict__ W2, const float* __restrict__ b2,
            float* __restrict__ feat1, float* __restrict__ rr1,
            float* __restrict__ samp1) {
  __shared__ float P[32][3];
  __shared__ float H[32][64];
  __shared__ float PM[4][64];
  const int tid = threadIdx.x;
  const int gq = blockIdx.x;                  // 0..4095
  const int b = gq >> 9, q = gq & (NS1-1);
  const float* xb = x + (size_t)b * NPTS * 3;
  const int* nb = idx1 + gq * KNN;
  if (tid < 96) { int n = tid/3, d = tid - n*3; P[n][d] = xb[nb[n]*3 + d]; }
  __syncthreads();
  #pragma unroll
  for (int i = 0; i < 8; ++i) {
    int e = tid + 256*i, n = e >> 6, c = e & 63;
    float h = b1[c] + P[n][0]*W1[c] + P[n][1]*W1[64+c] + P[n][2]*W1[128+c];
    H[n][c] = fmaxf(h, 0.0f);
  }
  __syncthreads();
  const int g = tid >> 6, c = tid & 63;
  float acc[8];
  #pragma unroll
  for (int k = 0; k < 8; ++k) acc[k] = 0.0f;
  for (int j = 0; j < 64; j += 4) {
    float w0 = W2[j*64+c], w1 = W2[(j+1)*64+c], w2 = W2[(j+2)*64+c], w3 = W2[(j+3)*64+c];
    #pragma unroll
    for (int k = 0; k < 8; ++k) {
      float4 h4 = *(const float4*)&H[g*8+k][j];
      acc[k] = fmaf(h4.w, w3, fmaf(h4.z, w2, fmaf(h4.y, w1, fmaf(h4.x, w0, acc[k]))));
    }
  }
  float m = acc[0];
  #pragma unroll
  for (int k = 1; k < 8; ++k) m = fmaxf(m, acc[k]);
  PM[g][c] = m;
  __syncthreads();
  if (tid < 64) {
    float v = fmaxf(fmaxf(PM[0][tid], PM[1][tid]), fmaxf(PM[2][tid], PM[3][tid])) + b2[tid];
    feat1[(size_t)gq*64 + tid] = v;
    float s = v*v;
    #pragma unroll
    for (int off = 32; off; off >>= 1) s += __shfl_xor(s, off);
    if (tid == 0) rr1[gq] = s;
  } else if (tid < 67) {
    int d = tid - 64;
    samp1[(size_t)gq*3 + d] = xb[sidx1[q]*3 + d];
  }
}

// ---- FUSED kNN2 + MLP2: block per query (1024 blocks).
extern "C" __global__ void __launch_bounds__(256)
knn2mlp2_kernel(const float* __restrict__ feat1, const float* __restrict__ rr1,
                const int* __restrict__ sidx2,
                const float* __restrict__ W1, const float* __restrict__ b1,
                const float* __restrict__ W2, const float* __restrict__ b2,
                float* __restrict__ feat2) {
  __shared__ float qrow[64];
  __shared__ float SK[4][32];
  __shared__ int   SI[4][32];
  __shared__ int   NBs[32];
  __shared__ float Gm[32][64];
  __shared__ float H[32][128];
  __shared__ float PM[2][128];
  const int tid = threadIdx.x, w = tid >> 6, lane = tid & 63;
  const int gq = blockIdx.x;                  // 0..1023
  const int b = gq >> 7, q = gq & (NS2-1);
  const float* f1b = feat1 + (size_t)b * NS1 * 64;
  const float* rrb = rr1 + b * NS1;
  const int sq = sidx2[q];
  if (tid < 64) qrow[tid] = f1b[sq*64 + tid];
  __syncthreads();
  const float qq = rrb[sq];
  float lkey = FINF, tau = FINF;
  int lidx = 0;
  #pragma unroll
  for (int t = 0; t < 2; ++t) {
    const int jb = w*128 + t*64;
    const int j = jb + lane;
    const float* rrow = f1b + j*64;
    float dot = 0.0f;
    #pragma unroll
    for (int f = 0; f < 64; f += 4) {
      float4 r4 = *(const float4*)(rrow + f);
      dot = fmaf(qrow[f+3], r4.w, fmaf(qrow[f+2], r4.z,
            fmaf(qrow[f+1], r4.y, fmaf(qrow[f+0], r4.x, dot))));
    }
    const float d = (qq - 2.0f*dot) + rrb[j];
    const unsigned long long mask = __ballot(d < tau);
    if (mask) topk32f_scan(d, jb, lane, lkey, lidx, tau, mask);
  }
  if (lane < 32) { SK[w][lane] = lkey; SI[w][lane] = lidx; }
  __syncthreads();
  if (w == 0) {
    #pragma unroll
    for (int ww = 1; ww < 4; ++ww) {
      const float mk = (lane < 32) ? SK[ww][lane] : FINF;
      const int   mi = (lane < 32) ? SI[ww][lane] : 0;
      const unsigned long long mmask = __ballot(mk < tau);
      if (mmask) topk32f_merge(mk, mi, lane, lkey, lidx, tau, mmask);
    }
    if (lane < 32) NBs[lane] = lidx;
  }
  __syncthreads();
  #pragma unroll
  for (int i = 0; i < 8; ++i) {
    int e = tid + 256*i, n = e >> 6, f = e & 63;
    Gm[n][f] = f1b[NBs[n]*64 + f];
  }
  __syncthreads();
  #pragma unroll
  for (int i = 0; i < 16; ++i) {
    int e = tid + 256*i, n = e >> 7, c = e & 127;
    float h = b1[c];
    for (int f = 0; f < 64; f += 4) {
      float4 g4 = *(const float4*)&Gm[n][f];
      h = fmaf(g4.x, W1[f*128+c], h);
      h = fmaf(g4.y, W1[(f+1)*128+c], h);
      h = fmaf(g4.z, W1[(f+2)*128+c], h);
      h = fmaf(g4.w, W1[(f+3)*128+c], h);
    }
    H[n][c] = fmaxf(h, 0.0f);
  }
  __syncthreads();
  const int g = tid >> 7, c = tid & 127;
  float acc[16];
  #pragma unroll
  for (int k = 0; k < 16; ++k) acc[k] = 0.0f;
  for (int j = 0; j < 128; j += 4) {
    float w0 = W2[j*128+c], w1 = W2[(j+1)*128+c], w2 = W2[(j+2)*128+c], w3 = W2[(j+3)*128+c];
    #pragma unroll
    for (int k = 0; k < 16; ++k) {
      float4 h4 = *(const float4*)&H[g*16+k][j];
      acc[k] = fmaf(h4.w, w3, fmaf(h4.z, w2, fmaf(h4.y, w1, fmaf(h4.x, w0, acc[k]))));
    }
  }
  float m = acc[0];
  #pragma unroll
  for (int k = 1; k < 16; ++k) m = fmaxf(m, acc[k]);
  PM[g][c] = m;
  __syncthreads();
  if (tid < 128) feat2[(size_t)gq*128 + tid] = fmaxf(PM[0][tid], PM[1][tid]) + b2[tid];
}

// ------- fp1: kNN(samp1 vs coords2, k=3) + mean(feat2) + MLP(192->64 relu ->64)
extern "C" __global__ void __launch_bounds__(256)
fp1_kernel(const float* __restrict__ samp1, const int* __restrict__ sidx2,
           const float* __restrict__ feat1, const float* __restrict__ feat2,
           const float* __restrict__ W1, const float* __restrict__ b1,
           const float* __restrict__ W2, const float* __restrict__ b2,
           float* __restrict__ h1) {
  __shared__ float interp[4][128];
  __shared__ float hbuf[4][64];
  const int w = threadIdx.x >> 6, lane = threadIdx.x & 63;
  const int gq = blockIdx.x*4 + w;            // 0..4095
  const int b = gq >> 9, q = gq & (NS1-1);
  const float* s1b = samp1 + (size_t)b * NS1 * 3;
  const float qx = s1b[q*3+0], qy = s1b[q*3+1], qz = s1b[q*3+2];
  const float qq = qx*qx + qy*qy + qz*qz;
  float d0, d1; int j0i, j1i;
  {
    const int rs = sidx2[lane];
    const float rx = s1b[rs*3+0], ry = s1b[rs*3+1], rz = s1b[rs*3+2];
    d0 = (qq - 2.0f*(qx*rx+qy*ry+qz*rz)) + (rx*rx+ry*ry+rz*rz);
    j0i = lane;
  }
  {
    const int j = lane + 64;
    const int rs = sidx2[j];
    const float rx = s1b[rs*3+0], ry = s1b[rs*3+1], rz = s1b[rs*3+2];
    d1 = (qq - 2.0f*(qx*rx+qy*ry+qz*rz)) + (rx*rx+ry*ry+rz*rz);
    j1i = j;
  }
  if (d1 < d0) { float td = d0; d0 = d1; d1 = td; int tj = j0i; j0i = j1i; j1i = tj; }
  float dA = d0, dB = d1, dC = FINF;
  int   jA = j0i, jB = j1i, jC = 0;
  merge3(dA, jA, dB, jB, dC, jC, 1);
  merge3(dA, jA, dB, jB, dC, jC, 2);
  merge3(dA, jA, dB, jB, dC, jC, 4);
  merge3(dA, jA, dB, jB, dC, jC, 8);
  merge3(dA, jA, dB, jB, dC, jC, 16);
  merge3(dA, jA, dB, jB, dC, jC, 32);
  const int r0 = jA, r1 = jB, r2 = jC;
  const float* f2b = feat2 + (size_t)b * NS2 * 128;
  interp[w][lane] =
      (f2b[r0*128+lane] + f2b[r1*128+lane] + f2b[r2*128+lane]) * (1.0f/3.0f);
  interp[w][lane+64] =
      (f2b[r0*128+64+lane] + f2b[r1*128+64+lane] + f2b[r2*128+64+lane]) * (1.0f/3.0f);
  __syncthreads();
  const float* f1row = feat1 + (size_t)gq * 64;
  float h = b1[lane];
  for (int f = 0; f < 64; ++f)  h = fmaf(f1row[f], W1[f*64+lane], h);
  for (int f = 0; f < 128; ++f) h = fmaf(interp[w][f], W1[(64+f)*64+lane], h);
  hbuf[w][lane] = fmaxf(h, 0.0f);
  __syncthreads();
  float o = b2[lane];
  for (int f = 0; f < 64; ++f) o = fmaf(hbuf[w][f], W2[f*64+lane], o);
  h1[(size_t)gq*64 + lane] = o;
}

// ---- FUSED fp2: 32 points/block, 8 threads/point kNN (64 refs each) + interp
// ---- + MLP(67->32 relu) @ folded (W2@fc) + sigmoid.
// RS is stored with one float4 pad per 64-entry group (phys = e + (e>>6)):
// group base = q8*65 float4s = 260 words -> bank 4*q8, so the 8 scan groups
// occupy disjoint 4-bank spans: conflict-free ds_read_b128.
extern "C" __global__ void __launch_bounds__(256, 5)
fp2_kernel(const float* __restrict__ x, const float* __restrict__ samp1,
           const float* __restrict__ h1,
           const float* __restrict__ W1, const float* __restrict__ b1,
           const float* __restrict__ W2, const float* __restrict__ b2,
           const float* __restrict__ fcW, const float* __restrict__ fcb,
           float* __restrict__ out) {
  __shared__ float4 RS[NS1 + 8];   // 8.1 KB, padded per 64-group
  __shared__ ushort4 kid[32];
  __shared__ float Xe[32][68];     // 8.7 KB
  __shared__ float W1s[67*32];     // 8.6 KB
  __shared__ float Hs[32][36];     // 4.6 KB
  __shared__ float WcS[64];
  __shared__ float bcS[2];
  const int tid = threadIdx.x;
  const int b = blockIdx.x >> 9;              // 512 blocks per batch
  const int pbase = (blockIdx.x & 511) * 32;
  const float* xb = x + (size_t)b * NPTS * 3;
  const float* h1b = h1 + (size_t)b * NS1 * 64;
  for (int e = tid; e < NS1; e += 256) {
    const float rx = samp1[((size_t)b*NS1 + e)*3 + 0];
    const float ry = samp1[((size_t)b*NS1 + e)*3 + 1];
    const float rz = samp1[((size_t)b*NS1 + e)*3 + 2];
    RS[e + (e >> 6)] = make_float4(rx, ry, rz, rx*rx + ry*ry + rz*rz);
  }
  for (int e = tid; e < 67*32; e += 256) W1s[e] = W1[e];
  if (tid < 96) {
    int n = tid/3, d = tid - n*3;
    Xe[n][d] = xb[(pbase+n)*3 + d];
  }
  __syncthreads();
  // ---- phase 1: top-3, 8 threads/point x 64 refs, 3-level shfl merge ----
  {
    const int pl = tid >> 3, q8 = tid & 7;
    const float qx = Xe[pl][0], qy = Xe[pl][1], qz = Xe[pl][2];
    const float qq = qx*qx + qy*qy + qz*qz;
    float d0 = FINF, d1 = FINF, d2 = FINF;
    int j0 = 0, j1 = 0, j2 = 0;
    const float4* RQ = RS + q8*65;            // padded group base
    #pragma unroll 4
    for (int i = 0; i < 64; ++i) {
      const float4 r = RQ[i];
      const float dot = qx*r.x + qy*r.y + qz*r.z;
      const float d = (qq - 2.0f*dot) + r.w;
      const int j = q8*64 + i;
      const bool c2 = d < d2, c1 = d < d1, c0 = d < d0;
      d2 = c1 ? d1 : (c2 ? d : d2);  j2 = c1 ? j1 : (c2 ? j : j2);
      d1 = c0 ? d0 : (c1 ? d : d1);  j1 = c0 ? j0 : (c1 ? j : j1);
      d0 = c0 ? d : d0;              j0 = c0 ? j : j0;
    }
    merge3(d0, j0, d1, j1, d2, j2, 1);
    merge3(d0, j0, d1, j1, d2, j2, 2);
    merge3(d0, j0, d1, j1, d2, j2, 4);
    if (q8 == 0) {
      ushort4 o;
      o.x = (unsigned short)j0; o.y = (unsigned short)j1;
      o.z = (unsigned short)j2; o.w = 0;
      kid[pl] = o;
    }
  }
  __syncthreads();
  // ---- phase 2: interp (32 pts x 64 feats) ----
  {
    const int sub = tid >> 6, f = tid & 63;
    #pragma unroll 4
    for (int i = 0; i < 8; ++i) {
      const int p = i*4 + sub;
      const ushort4 kk = kid[p];
      const float v = (h1b[(int)kk.x*64 + f] + h1b[(int)kk.y*64 + f] +
                       h1b[(int)kk.z*64 + f]) * (1.0f/3.0f);
      Xe[p][3+f] = v;
    }
  }
  __syncthreads();
  if (tid < 64) {
    const int k = tid >> 1, col = tid & 1;
    float s = 0.0f;
    for (int c = 0; c < 32; ++c) s = fmaf(W2[k*32+c], fcW[c*2+col], s);
    WcS[k*2+col] = s;
  } else if (tid < 66) {
    const int col = tid & 1;
    float s = fcb[col];
    for (int c = 0; c < 32; ++c) s = fmaf(b2[c], fcW[c*2+col], s);
    bcS[col] = s;
  }
  // ---- phase 3: hidden layer, 8 threads/point x 4 channels ----
  {
    const int p = tid >> 3, c0 = (tid & 7) * 4;
    float acc[4];
    const float4 bb = *(const float4*)(b1 + c0);
    acc[0]=bb.x; acc[1]=bb.y; acc[2]=bb.z; acc[3]=bb.w;
    for (int f = 0; f < 67; ++f) {
      const float xv = Xe[p][f];
      const float4 w0 = *(const float4*)&W1s[f*32 + c0];
      acc[0] = fmaf(xv, w0.x, acc[0]);
      acc[1] = fmaf(xv, w0.y, acc[1]);
      acc[2] = fmaf(xv, w0.z, acc[2]);
      acc[3] = fmaf(xv, w0.w, acc[3]);
    }
    *(float4*)&Hs[p][c0] = make_float4(fmaxf(acc[0],0.f), fmaxf(acc[1],0.f),
                                       fmaxf(acc[2],0.f), fmaxf(acc[3],0.f));
  }
  __syncthreads();
  // ---- phase 4: folded fc + sigmoid (32 pts x 2 cols) ----
  if (tid < 64) {
    const int p = tid >> 1, col = tid & 1;
    float s = bcS[col];
    for (int c = 0; c < 32; ++c) s = fmaf(Hs[p][c], WcS[c*2+col], s);
    out[((size_t)b*NPTS + pbase + p)*2 + col] = 1.0f / (1.0f + expf(-s));
  }
}

extern "C" void kernel_launch(void* const* d_in, const int* in_sizes, int n_in,
                              void* d_out, int out_size, void* d_ws, size_t ws_size,
                              hipStream_t stream) {
  const float* x     = (const float*)d_in[0];
  const int*   sidx1 = (const int*)d_in[1];
  const int*   sidx2 = (const int*)d_in[2];
  const float* sa1W1 = (const float*)d_in[3];
  const float* sa1b1 = (const float*)d_in[4];
  const float* sa1W2 = (const float*)d_in[5];
  const float* sa1b2 = (const float*)d_in[6];
  const float* sa2W1 = (const float*)d_in[7];
  const float* sa2b1 = (const float*)d_in[8];
  const float* sa2W2 = (const float*)d_in[9];
  const float* sa2b2 = (const float*)d_in[10];
  const float* fp1W1 = (const float*)d_in[11];
  const float* fp1b1 = (const float*)d_in[12];
  const float* fp1W2 = (const float*)d_in[13];
  const float* fp1b2 = (const float*)d_in[14];
  const float* fp2W1 = (const float*)d_in[15];
  const float* fp2b1 = (const float*)d_in[16];
  const float* fp2W2 = (const float*)d_in[17];
  const float* fp2b2 = (const float*)d_in[18];
  const float* fcW   = (const float*)d_in[19];
  const float* fcb   = (const float*)d_in[20];
  float* out = (float*)d_out;

  char* ws = (char*)d_ws;
  float4* xr   = (float4*)(ws + 0);         // 8*16384*16 = 2,097,152 B
  float* feat1 = (float*)(ws + 0);          // overlap: xr dead after knn1
  float* rr1   = (float*)(ws + 1048576);
  float* samp1 = (float*)(ws + 1064960);
  float* feat2 = (float*)(ws + 1114112);
  float* h1    = (float*)(ws + 1638400);
  int*   idx1  = (int*)  (ws + 2686976);

  hipLaunchKernelGGL(prep_kernel, dim3(512), dim3(256), 0, stream, x, xr);
  hipLaunchKernelGGL(knn1_kernel, dim3(1024), dim3(256), 0, stream,
                     xr, sidx1, idx1);
  hipLaunchKernelGGL(mlp1_kernel, dim3(4096), dim3(256), 0, stream,
                     x, sidx1, idx1, sa1W1, sa1b1, sa1W2, sa1b2,
                     feat1, rr1, samp1);
  hipLaunchKernelGGL(knn2mlp2_kernel, dim3(1024), dim3(256), 0, stream,
                     feat1, rr1, sidx2, sa2W1, sa2b1, sa2W2, sa2b2, feat2);
  hipLaunchKernelGGL(fp1_kernel, dim3(1024), dim3(256), 0, stream,
                     samp1, sidx2, feat1, feat2, fp1W1, fp1b1, fp1W2, fp1b2, h1);
  hipLaunchKernelGGL(fp2_kernel, dim3(4096), dim3(256), 0, stream,
                     x, samp1, h1, fp2W1, fp2b1, fp2W2, fp2b2, fcW, fcb, out);
}

// Round 17
// 235.224 us; speedup vs baseline: 1.1329x; 1.0029x over previous
//
#include <hip/hip_runtime.h>
#include <hip/hip_bf16.h>

#define NB   8
#define NPTS 16384
#define NS1  512
#define NS2  128
#define KNN  32
#define FINF 3.402823466e+38f
#define NINF_BITS ((int)0xFF800000)

// Distributed exact running top-32 across lanes 0..31: f32 key + carried idx.
// STABLE insert + strict < vs tau == lexicographic (d, idx) when candidates
// arrive in ascending idx order. Scan variant: candidate idx = jbase + src.
__device__ __forceinline__ void topk32f_scan(float key, int jbase, int lane,
                                             float& lkey, int& lidx, float& tau,
                                             unsigned long long mask) {
  const bool is16 = (lane == 16);
  while (mask) {
    const int src = (int)(__ffsll((long long)mask) - 1);   // wave-uniform
    mask &= mask - 1;
    const float ck = __int_as_float(
        __builtin_amdgcn_readlane(__float_as_int(key), src));
    if (ck < tau) {
      const int ci = jbase + src;                          // SALU, no readlane
      const int upk0 = __builtin_amdgcn_update_dpp(
          NINF_BITS, __float_as_int(lkey), 0x111, 0xf, 0xf, false);
      const int upi0 = __builtin_amdgcn_update_dpp(
          0, lidx, 0x111, 0xf, 0xf, false);
      const int pk = __builtin_amdgcn_readlane(__float_as_int(lkey), 15);
      const int pi = __builtin_amdgcn_readlane(lidx, 15);
      const float up  = __int_as_float(is16 ? pk : upk0);
      const int   upi = is16 ? pi : upi0;
      const bool keep  = (lkey <= ck);
      const bool useup = (up > ck);
      const float nk = keep ? lkey : (useup ? up : ck);
      const int   ni = keep ? lidx : (useup ? upi : ci);
      if (lane < 32) { lkey = nk; lidx = ni; }
      tau = __int_as_float(__builtin_amdgcn_readlane(__float_as_int(lkey), 31));
    }
  }
}

// Merge variant: candidate idx is arbitrary (gathered) -> readlane it.
__device__ __forceinline__ void topk32f_merge(float key, int idx, int lane,
                                              float& lkey, int& lidx, float& tau,
                                              unsigned long long mask) {
  const bool is16 = (lane == 16);
  while (mask) {
    const int src = (int)(__ffsll((long long)mask) - 1);
    mask &= mask - 1;
    const float ck = __int_as_float(
        __builtin_amdgcn_readlane(__float_as_int(key), src));
    if (ck < tau) {
      const int ci = __builtin_amdgcn_readlane(idx, src);
      const int upk0 = __builtin_amdgcn_update_dpp(
          NINF_BITS, __float_as_int(lkey), 0x111, 0xf, 0xf, false);
      const int upi0 = __builtin_amdgcn_update_dpp(
          0, lidx, 0x111, 0xf, 0xf, false);
      const int pk = __builtin_amdgcn_readlane(__float_as_int(lkey), 15);
      const int pi = __builtin_amdgcn_readlane(lidx, 15);
      const float up  = __int_as_float(is16 ? pk : upk0);
      const int   upi = is16 ? pi : upi0;
      const bool keep  = (lkey <= ck);
      const bool useup = (up > ck);
      const float nk = keep ? lkey : (useup ? up : ck);
      const int   ni = keep ? lidx : (useup ? upi : ci);
      if (lane < 32) { lkey = nk; lidx = ni; }
      tau = __int_as_float(__builtin_amdgcn_readlane(__float_as_int(lkey), 31));
    }
  }
}

// Merge this lane's sorted top-3 (d,j) with xor-partner's, lexicographic (d, j).
__device__ __forceinline__ void merge3(float& d0, int& j0, float& d1, int& j1,
                                       float& d2, int& j2, int xm) {
  float e0 = __shfl_xor(d0, xm), e1 = __shfl_xor(d1, xm), e2 = __shfl_xor(d2, xm);
  int   f0 = __shfl_xor(j0, xm), f1 = __shfl_xor(j1, xm), f2 = __shfl_xor(j2, xm);
  float a0 = d0, a1 = d1, a2 = d2;
  int   b0 = j0, b1 = j1, b2 = j2;
  float od0, od1, od2; int oj0, oj1, oj2;
  #pragma unroll
  for (int r = 0; r < 3; ++r) {
    bool ta = (a0 < e0) || (a0 == e0 && b0 < f0);
    float sd = ta ? a0 : e0; int sj = ta ? b0 : f0;
    a0 = ta ? a1 : a0;  b0 = ta ? b1 : b0;
    a1 = ta ? a2 : a1;  b1 = ta ? b2 : b1;
    a2 = ta ? FINF : a2;
    e0 = ta ? e0 : e1;  f0 = ta ? f0 : f1;
    e1 = ta ? e1 : e2;  f1 = ta ? f1 : f2;
    e2 = ta ? e2 : FINF;
    if (r == 0) { od0 = sd; oj0 = sj; }
    else if (r == 1) { od1 = sd; oj1 = sj; }
    else { od2 = sd; oj2 = sj; }
  }
  d0 = od0; j0 = oj0; d1 = od1; j1 = oj1; d2 = od2; j2 = oj2;
}

// ---------------- prep: xr[i] = (x, y, z, x^2+y^2+z^2) for all B*N points ----
extern "C" __global__ void __launch_bounds__(256)
prep_kernel(const float* __restrict__ x, float4* __restrict__ xr) {
  const int i = blockIdx.x * 256 + threadIdx.x;   // 0..131071
  const float rx = x[i*3+0], ry = x[i*3+1], rz = x[i*3+2];
  xr[i] = make_float4(rx, ry, rz, rx*rx + ry*ry + rz*rz);
}

// per-tile distance + top-32 maintenance (f32 key, idx = jbase + src)
#define PROCF(rr, jbase)                                                      \
  {                                                                           \
    const float d = (Q.w - 2.0f*(Q.x*rr.x + Q.y*rr.y + Q.z*rr.z)) + rr.w;     \
    const unsigned long long mask = __ballot(d < tau);                        \
    if (mask) topk32f_scan(d, (jbase), lane, lkey, lidx, tau, mask);          \
  }

// ---- kNN 1: wave-per-query, 8-deep prefetch ring, per-insert tau,
// ---- 32-bit f32 stable insert (DPP + readlane; no LDS). [R11-proven: 88us]
extern "C" __global__ void __launch_bounds__(256)
knn1_kernel(const float4* __restrict__ xr, const int* __restrict__ sidx1,
            int* __restrict__ idx1) {
  const int w = threadIdx.x >> 6, lane = threadIdx.x & 63;
  const int gq = blockIdx.x * 4 + w;          // 0..4095
  const int b = gq >> 9, q = gq & (NS1 - 1);
  const float4* xb = xr + (size_t)b * NPTS;
  const float4 Q = xb[sidx1[q]];
  float lkey = FINF, tau = FINF;
  int lidx = 0;
  float4 r0 = xb[0*64+lane], r1 = xb[1*64+lane], r2 = xb[2*64+lane], r3 = xb[3*64+lane];
  float4 r4 = xb[4*64+lane], r5 = xb[5*64+lane], r6 = xb[6*64+lane], r7 = xb[7*64+lane];
  for (int t = 0; t < 256; t += 8) {
    PROCF(r0, (t+0)*64);  r0 = xb[((t+ 8)&255)*64 + lane];
    PROCF(r1, (t+1)*64);  r1 = xb[((t+ 9)&255)*64 + lane];
    PROCF(r2, (t+2)*64);  r2 = xb[((t+10)&255)*64 + lane];
    PROCF(r3, (t+3)*64);  r3 = xb[((t+11)&255)*64 + lane];
    PROCF(r4, (t+4)*64);  r4 = xb[((t+12)&255)*64 + lane];
    PROCF(r5, (t+5)*64);  r5 = xb[((t+13)&255)*64 + lane];
    PROCF(r6, (t+6)*64);  r6 = xb[((t+14)&255)*64 + lane];
    PROCF(r7, (t+7)*64);  r7 = xb[((t+15)&255)*64 + lane];
  }
  if (lane < 32) idx1[gq*KNN + lane] = lidx;
}

// ---------------- MLP1 (3->64 relu ->64) + maxpool over 32 nbrs ---------------
extern "C" __global__ void __launch_bounds__(256)
mlp1_kernel(const float* __restrict__ x, const int* __restrict__ sidx1,
            const int* __restrict__ idx1,
            const float* __restrict__ W1, const float* __restrict__ b1,
            const float* __restrict__ W2, const float* __restrict__ b2,
            float* __restrict__ feat1, float* __restrict__ rr1,
            float* __restrict__ samp1) {
  __shared__ float P[32][3];
  __shared__ float H[32][64];
  __shared__ float PM[4][64];
  const int tid = threadIdx.x;
  const int gq = blockIdx.x;                  // 0..4095
  const int b = gq >> 9, q = gq & (NS1-1);
  const float* xb = x + (size_t)b * NPTS * 3;
  const int* nb = idx1 + gq * KNN;
  if (tid < 96) { int n = tid/3, d = tid - n*3; P[n][d] = xb[nb[n]*3 + d]; }
  __syncthreads();
  #pragma unroll
  for (int i = 0; i < 8; ++i) {
    int e = tid + 256*i, n = e >> 6, c = e & 63;
    float h = b1[c] + P[n][0]*W1[c] + P[n][1]*W1[64+c] + P[n][2]*W1[128+c];
    H[n][c] = fmaxf(h, 0.0f);
  }
  __syncthreads();
  const int g = tid >> 6, c = tid & 63;
  float acc[8];
  #pragma unroll
  for (int k = 0; k < 8; ++k) acc[k] = 0.0f;
  for (int j = 0; j < 64; j += 4) {
    float w0 = W2[j*64+c], w1 = W2[(j+1)*64+c], w2 = W2[(j+2)*64+c], w3 = W2[(j+3)*64+c];
    #pragma unroll
    for (int k = 0; k < 8; ++k) {
      float4 h4 = *(const float4*)&H[g*8+k][j];
      acc[k] = fmaf(h4.w, w3, fmaf(h4.z, w2, fmaf(h4.y, w1, fmaf(h4.x, w0, acc[k]))));
    }
  }
  float m = acc[0];
  #pragma unroll
  for (int k = 1; k < 8; ++k) m = fmaxf(m, acc[k]);
  PM[g][c] = m;
  __syncthreads();
  if (tid < 64) {
    float v = fmaxf(fmaxf(PM[0][tid], PM[1][tid]), fmaxf(PM[2][tid], PM[3][tid])) + b2[tid];
    feat1[(size_t)gq*64 + tid] = v;
    float s = v*v;
    #pragma unroll
    for (int off = 32; off; off >>= 1) s += __shfl_xor(s, off);
    if (tid == 0) rr1[gq] = s;
  } else if (tid < 67) {
    int d = tid - 64;
    samp1[(size_t)gq*3 + d] = xb[sidx1[q]*3 + d];
  }
}

// ---- FUSED kNN2 + MLP2: block per query (1024 blocks).
extern "C" __global__ void __launch_bounds__(256)
knn2mlp2_kernel(const float* __restrict__ feat1, const float* __restrict__ rr1,
                const int* __restrict__ sidx2,
                const float* __restrict__ W1, const float* __restrict__ b1,
                const float* __restrict__ W2, const float* __restrict__ b2,
                float* __restrict__ feat2) {
  __shared__ float qrow[64];
  __shared__ float SK[4][32];
  __shared__ int   SI[4][32];
  __shared__ int   NBs[32];
  __shared__ float Gm[32][64];
  __shared__ float H[32][128];
  __shared__ float PM[2][128];
  const int tid = threadIdx.x, w = tid >> 6, lane = tid & 63;
  const int gq = blockIdx.x;                  // 0..1023
  const int b = gq >> 7, q = gq & (NS2-1);
  const float* f1b = feat1 + (size_t)b * NS1 * 64;
  const float* rrb = rr1 + b * NS1;
  const int sq = sidx2[q];
  if (tid < 64) qrow[tid] = f1b[sq*64 + tid];
  __syncthreads();
  const float qq = rrb[sq];
  float lkey = FINF, tau = FINF;
  int lidx = 0;
  #pragma unroll
  for (int t = 0; t < 2; ++t) {
    const int jb = w*128 + t*64;
    const int j = jb + lane;
    const float* rrow = f1b + j*64;
    float dot = 0.0f;
    #pragma unroll
    for (int f = 0; f < 64; f += 4) {
      float4 r4 = *(const float4*)(rrow + f);
      dot = fmaf(qrow[f+3], r4.w, fmaf(qrow[f+2], r4.z,
            fmaf(qrow[f+1], r4.y, fmaf(qrow[f+0], r4.x, dot))));
    }
    const float d = (qq - 2.0f*dot) + rrb[j];
    const unsigned long long mask = __ballot(d < tau);
    if (mask) topk32f_scan(d, jb, lane, lkey, lidx, tau, mask);
  }
  if (lane < 32) { SK[w][lane] = lkey; SI[w][lane] = lidx; }
  __syncthreads();
  if (w == 0) {
    #pragma unroll
    for (int ww = 1; ww < 4; ++ww) {
      const float mk = (lane < 32) ? SK[ww][lane] : FINF;
      const int   mi = (lane < 32) ? SI[ww][lane] : 0;
      const unsigned long long mmask = __ballot(mk < tau);
      if (mmask) topk32f_merge(mk, mi, lane, lkey, lidx, tau, mmask);
    }
    if (lane < 32) NBs[lane] = lidx;
  }
  __syncthreads();
  #pragma unroll
  for (int i = 0; i < 8; ++i) {
    int e = tid + 256*i, n = e >> 6, f = e & 63;
    Gm[n][f] = f1b[NBs[n]*64 + f];
  }
  __syncthreads();
  #pragma unroll
  for (int i = 0; i < 16; ++i) {
    int e = tid + 256*i, n = e >> 7, c = e & 127;
    float h = b1[c];
    for (int f = 0; f < 64; f += 4) {
      float4 g4 = *(const float4*)&Gm[n][f];
      h = fmaf(g4.x, W1[f*128+c], h);
      h = fmaf(g4.y, W1[(f+1)*128+c], h);
      h = fmaf(g4.z, W1[(f+2)*128+c], h);
      h = fmaf(g4.w, W1[(f+3)*128+c], h);
    }
    H[n][c] = fmaxf(h, 0.0f);
  }
  __syncthreads();
  const int g = tid >> 7, c = tid & 127;
  float acc[16];
  #pragma unroll
  for (int k = 0; k < 16; ++k) acc[k] = 0.0f;
  for (int j = 0; j < 128; j += 4) {
    float w0 = W2[j*128+c], w1 = W2[(j+1)*128+c], w2 = W2[(j+2)*128+c], w3 = W2[(j+3)*128+c];
    #pragma unroll
    for (int k = 0; k < 16; ++k) {
      float4 h4 = *(const float4*)&H[g*16+k][j];
      acc[k] = fmaf(h4.w, w3, fmaf(h4.z, w2, fmaf(h4.y, w1, fmaf(h4.x, w0, acc[k]))));
    }
  }
  float m = acc[0];
  #pragma unroll
  for (int k = 1; k < 16; ++k) m = fmaxf(m, acc[k]);
  PM[g][c] = m;
  __syncthreads();
  if (tid < 128) feat2[(size_t)gq*128 + tid] = fmaxf(PM[0][tid], PM[1][tid]) + b2[tid];
}

// ------- fp1: kNN(samp1 vs coords2, k=3) + mean(feat2) + MLP(192->64 relu ->64)
extern "C" __global__ void __launch_bounds__(256)
fp1_kernel(const float* __restrict__ samp1, const int* __restrict__ sidx2,
           const float* __restrict__ feat1, const float* __restrict__ feat2,
           const float* __restrict__ W1, const float* __restrict__ b1,
           const float* __restrict__ W2, const float* __restrict__ b2,
           float* __restrict__ h1) {
  __shared__ float interp[4][128];
  __shared__ float hbuf[4][64];
  const int w = threadIdx.x >> 6, lane = threadIdx.x & 63;
  const int gq = blockIdx.x*4 + w;            // 0..4095
  const int b = gq >> 9, q = gq & (NS1-1);
  const float* s1b = samp1 + (size_t)b * NS1 * 3;
  const float qx = s1b[q*3+0], qy = s1b[q*3+1], qz = s1b[q*3+2];
  const float qq = qx*qx + qy*qy + qz*qz;
  float d0, d1; int j0i, j1i;
  {
    const int rs = sidx2[lane];
    const float rx = s1b[rs*3+0], ry = s1b[rs*3+1], rz = s1b[rs*3+2];
    d0 = (qq - 2.0f*(qx*rx+qy*ry+qz*rz)) + (rx*rx+ry*ry+rz*rz);
    j0i = lane;
  }
  {
    const int j = lane + 64;
    const int rs = sidx2[j];
    const float rx = s1b[rs*3+0], ry = s1b[rs*3+1], rz = s1b[rs*3+2];
    d1 = (qq - 2.0f*(qx*rx+qy*ry+qz*rz)) + (rx*rx+ry*ry+rz*rz);
    j1i = j;
  }
  if (d1 < d0) { float td = d0; d0 = d1; d1 = td; int tj = j0i; j0i = j1i; j1i = tj; }
  float dA = d0, dB = d1, dC = FINF;
  int   jA = j0i, jB = j1i, jC = 0;
  merge3(dA, jA, dB, jB, dC, jC, 1);
  merge3(dA, jA, dB, jB, dC, jC, 2);
  merge3(dA, jA, dB, jB, dC, jC, 4);
  merge3(dA, jA, dB, jB, dC, jC, 8);
  merge3(dA, jA, dB, jB, dC, jC, 16);
  merge3(dA, jA, dB, jB, dC, jC, 32);
  const int r0 = jA, r1 = jB, r2 = jC;
  const float* f2b = feat2 + (size_t)b * NS2 * 128;
  interp[w][lane] =
      (f2b[r0*128+lane] + f2b[r1*128+lane] + f2b[r2*128+lane]) * (1.0f/3.0f);
  interp[w][lane+64] =
      (f2b[r0*128+64+lane] + f2b[r1*128+64+lane] + f2b[r2*128+64+lane]) * (1.0f/3.0f);
  __syncthreads();
  const float* f1row = feat1 + (size_t)gq * 64;
  float h = b1[lane];
  for (int f = 0; f < 64; ++f)  h = fmaf(f1row[f], W1[f*64+lane], h);
  for (int f = 0; f < 128; ++f) h = fmaf(interp[w][f], W1[(64+f)*64+lane], h);
  hbuf[w][lane] = fmaxf(h, 0.0f);
  __syncthreads();
  float o = b2[lane];
  for (int f = 0; f < 64; ++f) o = fmaf(hbuf[w][f], W2[f*64+lane], o);
  h1[(size_t)gq*64 + lane] = o;
}

// ---- FUSED fp2: 32 points/block, 8 threads/point kNN (64 refs each) + interp
// ---- + MLP(67->32 relu) @ folded (W2@fc) + sigmoid.
// RS is stored with one float4 pad per 64-entry group (phys = e + (e>>6)):
// group base = q8*65 float4s = 260 words -> bank 4*q8, so the 8 scan groups
// occupy disjoint 4-bank spans: conflict-free ds_read_b128.
extern "C" __global__ void __launch_bounds__(256, 5)
fp2_kernel(const float* __restrict__ x, const float* __restrict__ samp1,
           const float* __restrict__ h1,
           const float* __restrict__ W1, const float* __restrict__ b1,
           const float* __restrict__ W2, const float* __restrict__ b2,
           const float* __restrict__ fcW, const float* __restrict__ fcb,
           float* __restrict__ out) {
  __shared__ float4 RS[NS1 + 8];   // 8.1 KB, padded per 64-group
  __shared__ ushort4 kid[32];
  __shared__ float Xe[32][68];     // 8.7 KB
  __shared__ float W1s[67*32];     // 8.6 KB
  __shared__ float Hs[32][36];     // 4.6 KB
  __shared__ float WcS[64];
  __shared__ float bcS[2];
  const int tid = threadIdx.x;
  const int b = blockIdx.x >> 9;              // 512 blocks per batch
  const int pbase = (blockIdx.x & 511) * 32;
  const float* xb = x + (size_t)b * NPTS * 3;
  const float* h1b = h1 + (size_t)b * NS1 * 64;
  for (int e = tid; e < NS1; e += 256) {
    const float rx = samp1[((size_t)b*NS1 + e)*3 + 0];
    const float ry = samp1[((size_t)b*NS1 + e)*3 + 1];
    const float rz = samp1[((size_t)b*NS1 + e)*3 + 2];
    RS[e + (e >> 6)] = make_float4(rx, ry, rz, rx*rx + ry*ry + rz*rz);
  }
  for (int e = tid; e < 67*32; e += 256) W1s[e] = W1[e];
  if (tid < 96) {
    int n = tid/3, d = tid - n*3;
    Xe[n][d] = xb[(pbase+n)*3 + d];
  }
  __syncthreads();
  // ---- phase 1: top-3, 8 threads/point x 64 refs, 3-level shfl merge ----
  {
    const int pl = tid >> 3, q8 = tid & 7;
    const float qx = Xe[pl][0], qy = Xe[pl][1], qz = Xe[pl][2];
    const float qq = qx*qx + qy*qy + qz*qz;
    float d0 = FINF, d1 = FINF, d2 = FINF;
    int j0 = 0, j1 = 0, j2 = 0;
    const float4* RQ = RS + q8*65;            // padded group base
    #pragma unroll 4
    for (int i = 0; i < 64; ++i) {
      const float4 r = RQ[i];
      const float dot = qx*r.x + qy*r.y + qz*r.z;
      const float d = (qq - 2.0f*dot) + r.w;
      const int j = q8*64 + i;
      const bool c2 = d < d2, c1 = d < d1, c0 = d < d0;
      d2 = c1 ? d1 : (c2 ? d : d2);  j2 = c1 ? j1 : (c2 ? j : j2);
      d1 = c0 ? d0 : (c1 ? d : d1);  j1 = c0 ? j0 : (c1 ? j : j1);
      d0 = c0 ? d : d0;              j0 = c0 ? j : j0;
    }
    merge3(d0, j0, d1, j1, d2, j2, 1);
    merge3(d0, j0, d1, j1, d2, j2, 2);
    merge3(d0, j0, d1, j1, d2, j2, 4);
    if (q8 == 0) {
      ushort4 o;
      o.x = (unsigned short)j0; o.y = (unsigned short)j1;
      o.z = (unsigned short)j2; o.w = 0;
      kid[pl] = o;
    }
  }
  __syncthreads();
  // ---- phase 2: interp (32 pts x 64 feats) ----
  {
    const int sub = tid >> 6, f = tid & 63;
    #pragma unroll 4
    for (int i = 0; i < 8; ++i) {
      const int p = i*4 + sub;
      const ushort4 kk = kid[p];
      const float v = (h1b[(int)kk.x*64 + f] + h1b[(int)kk.y*64 + f] +
                       h1b[(int)kk.z*64 + f]) * (1.0f/3.0f);
      Xe[p][3+f] = v;
    }
  }
  __syncthreads();
  if (tid < 64) {
    const int k = tid >> 1, col = tid & 1;
    float s = 0.0f;
    for (int c = 0; c < 32; ++c) s = fmaf(W2[k*32+c], fcW[c*2+col], s);
    WcS[k*2+col] = s;
  } else if (tid < 66) {
    const int col = tid & 1;
    float s = fcb[col];
    for (int c = 0; c < 32; ++c) s = fmaf(b2[c], fcW[c*2+col], s);
    bcS[col] = s;
  }
  // ---- phase 3: hidden layer, 8 threads/point x 4 channels ----
  {
    const int p = tid >> 3, c0 = (tid & 7) * 4;
    float acc[4];
    const float4 bb = *(const float4*)(b1 + c0);
    acc[0]=bb.x; acc[1]=bb.y; acc[2]=bb.z; acc[3]=bb.w;
    for (int f = 0; f < 67; ++f) {
      const float xv = Xe[p][f];
      const float4 w0 = *(const float4*)&W1s[f*32 + c0];
      acc[0] = fmaf(xv, w0.x, acc[0]);
      acc[1] = fmaf(xv, w0.y, acc[1]);
      acc[2] = fmaf(xv, w0.z, acc[2]);
      acc[3] = fmaf(xv, w0.w, acc[3]);
    }
    *(float4*)&Hs[p][c0] = make_float4(fmaxf(acc[0],0.f), fmaxf(acc[1],0.f),
                                       fmaxf(acc[2],0.f), fmaxf(acc[3],0.f));
  }
  __syncthreads();
  // ---- phase 4: folded fc + sigmoid (32 pts x 2 cols) ----
  if (tid < 64) {
    const int p = tid >> 1, col = tid & 1;
    float s = bcS[col];
    for (int c = 0; c < 32; ++c) s = fmaf(Hs[p][c], WcS[c*2+col], s);
    out[((size_t)b*NPTS + pbase + p)*2 + col] = 1.0f / (1.0f + expf(-s));
  }
}

extern "C" void kernel_launch(void* const* d_in, const int* in_sizes, int n_in,
                              void* d_out, int out_size, void* d_ws, size_t ws_size,
                              hipStream_t stream) {
  const float* x     = (const float*)d_in[0];
  const int*   sidx1 = (const int*)d_in[1];
  const int*   sidx2 = (const int*)d_in[2];
  const float* sa1W1 = (const float*)d_in[3];
  const float* sa1b1 = (const float*)d_in[4];
  const float* sa1W2 = (const float*)d_in[5];
  const float* sa1b2 = (const float*)d_in[6];
  const float* sa2W1 = (const float*)d_in[7];
  const float* sa2b1 = (const float*)d_in[8];
  const float* sa2W2 = (const float*)d_in[9];
  const float* sa2b2 = (const float*)d_in[10];
  const float* fp1W1 = (const float*)d_in[11];
  const float* fp1b1 = (const float*)d_in[12];
  const float* fp1W2 = (const float*)d_in[13];
  const float* fp1b2 = (const float*)d_in[14];
  const float* fp2W1 = (const float*)d_in[15];
  const float* fp2b1 = (const float*)d_in[16];
  const float* fp2W2 = (const float*)d_in[17];
  const float* fp2b2 = (const float*)d_in[18];
  const float* fcW   = (const float*)d_in[19];
  const float* fcb   = (const float*)d_in[20];
  float* out = (float*)d_out;

  char* ws = (char*)d_ws;
  float4* xr   = (float4*)(ws + 0);         // 8*16384*16 = 2,097,152 B
  float* feat1 = (float*)(ws + 0);          // overlap: xr dead after knn1
  float* rr1   = (float*)(ws + 1048576);
  float* samp1 = (float*)(ws + 1064960);
  float* feat2 = (float*)(ws + 1114112);
  float* h1    = (float*)(ws + 1638400);
  int*   idx1  = (int*)  (ws + 2686976);

  hipLaunchKernelGGL(prep_kernel, dim3(512), dim3(256), 0, stream, x, xr);
  hipLaunchKernelGGL(knn1_kernel, dim3(1024), dim3(256), 0, stream,
                     xr, sidx1, idx1);
  hipLaunchKernelGGL(mlp1_kernel, dim3(4096), dim3(256), 0, stream,
                     x, sidx1, idx1, sa1W1, sa1b1, sa1W2, sa1b2,
                     feat1, rr1, samp1);
  hipLaunchKernelGGL(knn2mlp2_kernel, dim3(1024), dim3(256), 0, stream,
                     feat1, rr1, sidx2, sa2W1, sa2b1, sa2W2, sa2b2, feat2);
  hipLaunchKernelGGL(fp1_kernel, dim3(1024), dim3(256), 0, stream,
                     samp1, sidx2, feat1, feat2, fp1W1, fp1b1, fp1W2, fp1b2, h1);
  hipLaunchKernelGGL(fp2_kernel, dim3(4096), dim3(256), 0, stream,
                     x, samp1, h1, fp2W1, fp2b1, fp2W2, fp2b2, fcW, fcb, out);
}